// Round 1
// baseline (2627.505 us; speedup 1.0000x reference)
//
#include <hip/hip_runtime.h>
#include <math.h>

#define BATCH 2048
#define CIN 14
#define LEN 2048
#define NB 4
#define HID 64
#define NEG 0.01f

// fast activations (f32, ~2ulp via v_exp_f32)
__device__ __forceinline__ float sigm_f(float x) { return 1.0f / (1.0f + __expf(-x)); }
__device__ __forceinline__ float tanh_f(float x) { return 1.0f - 2.0f / (1.0f + __expf(2.0f * x)); }

// ---------------- Kernel A: pool (hierarchical) + conv1d(k=3,pad=1) + LeakyReLU ----------------
// writes xc[bin] in layout [t][b][4] at element offsets binoff[bin]

__device__ __forceinline__ void conv_bin(const float* __restrict__ P, int ldp, int T,
                                         int bin, size_t binoff,
                                         const float* __restrict__ cw,
                                         const float* __restrict__ cb,
                                         float* __restrict__ xc, int b, int tid)
{
    const float* w = cw + (size_t)bin * 4 * CIN * 3;   // w[(f*CIN+ci)*3 + k]
    const float b0 = cb[bin * 4 + 0];
    const float b1 = cb[bin * 4 + 1];
    const float b2 = cb[bin * 4 + 2];
    const float b3 = cb[bin * 4 + 3];
    for (int t = tid; t < T; t += 256) {
        float a0 = b0, a1 = b1, a2 = b2, a3 = b3;
        for (int ci = 0; ci < CIN; ++ci) {
            float pm = (t > 0)     ? P[ci * ldp + t - 1] : 0.0f;
            float p0 =               P[ci * ldp + t];
            float pp = (t < T - 1) ? P[ci * ldp + t + 1] : 0.0f;
            const float* w0 = w + (0 * CIN + ci) * 3;
            const float* w1 = w + (1 * CIN + ci) * 3;
            const float* w2 = w + (2 * CIN + ci) * 3;
            const float* w3 = w + (3 * CIN + ci) * 3;
            a0 += w0[0] * pm + w0[1] * p0 + w0[2] * pp;
            a1 += w1[0] * pm + w1[1] * p0 + w1[2] * pp;
            a2 += w2[0] * pm + w2[1] * p0 + w2[2] * pp;
            a3 += w3[0] * pm + w3[1] * p0 + w3[2] * pp;
        }
        a0 = (a0 >= 0.0f) ? a0 : NEG * a0;
        a1 = (a1 >= 0.0f) ? a1 : NEG * a1;
        a2 = (a2 >= 0.0f) ? a2 : NEG * a2;
        a3 = (a3 >= 0.0f) ? a3 : NEG * a3;
        float4 o = make_float4(a0, a1, a2, a3);
        *reinterpret_cast<float4*>(xc + binoff + ((size_t)t * BATCH + b) * 4) = o;
    }
}

__global__ __launch_bounds__(256) void pool_conv_kernel(
    const float* __restrict__ X, const float* __restrict__ cw,
    const float* __restrict__ cb, float* __restrict__ xc)
{
    __shared__ float Pa[CIN][512];
    __shared__ float Pb[CIN][256];
    const int b = blockIdx.x;
    const int tid = threadIdx.x;

    // pool 2048 -> 512 (kernel == stride == 4), coalesced float4 reads
    for (int idx = tid; idx < CIN * 512; idx += 256) {
        int c = idx >> 9, t = idx & 511;
        const float4 v = *reinterpret_cast<const float4*>(X + ((size_t)b * CIN + c) * LEN + 4 * t);
        Pa[c][t] = 0.25f * (v.x + v.y + v.z + v.w);
    }
    __syncthreads();

    // bin 0 (T=512) from Pa; also derive P256 -> Pb (both only READ Pa)
    conv_bin(&Pa[0][0], 512, 512, 0, 0, cw, cb, xc, b, tid);
    for (int idx = tid; idx < CIN * 256; idx += 256) {
        int c = idx >> 8, t = idx & 255;
        Pb[c][t] = 0.5f * (Pa[c][2 * t] + Pa[c][2 * t + 1]);
    }
    __syncthreads();

    // bin 1 (T=256) from Pb; derive P128 into front of Pa (ldp stays 512)
    conv_bin(&Pb[0][0], 256, 256, 1, 4194304, cw, cb, xc, b, tid);
    for (int idx = tid; idx < CIN * 128; idx += 256) {
        int c = idx >> 7, t = idx & 127;
        Pa[c][t] = 0.5f * (Pb[c][2 * t] + Pb[c][2 * t + 1]);
    }
    __syncthreads();

    // bin 2 (T=128) from Pa-front; derive P64 into front of Pb
    conv_bin(&Pa[0][0], 512, 128, 2, 6291456, cw, cb, xc, b, tid);
    for (int idx = tid; idx < CIN * 64; idx += 256) {
        int c = idx >> 6, t = idx & 63;
        Pb[c][t] = 0.5f * (Pa[c][2 * t] + Pa[c][2 * t + 1]);
    }
    __syncthreads();

    // bin 3 (T=64) from Pb-front
    conv_bin(&Pb[0][0], 256, 64, 3, 7340032, cw, cb, xc, b, tid);
}

// ---------------- Kernel B: LSTM scan + linear head ----------------
// 1024 blocks: bin = blockIdx.x & 3, batch group of 8 = blockIdx.x >> 2
// thread j (0..255) owns gate row j (w_hh row in 64 VGPRs).
// h in LDS (broadcast reads); c in registers of the updating thread.

__global__ __launch_bounds__(256, 2) void lstm_kernel(
    const float* __restrict__ xc,
    const float* __restrict__ wih, const float* __restrict__ whh,
    const float* __restrict__ bih, const float* __restrict__ bhh,
    const float* __restrict__ lw, const float* __restrict__ lb,
    float* __restrict__ out)
{
    __shared__ float4 h4[8][16];      // h[8 batch][64]
    __shared__ float gbuf[8][256];    // activated gates [batch][row]
    __shared__ float4 xt4[256];       // x tile: 32 steps x 8 batch x 4ch

    const int tid = threadIdx.x;
    const int bin = blockIdx.x & 3;
    const int grp = blockIdx.x >> 2;
    const int b0 = grp * 8;
    const int Ts[NB] = {512, 256, 128, 64};
    const size_t offs[NB] = {0, 4194304, 6291456, 7340032};
    const int T = Ts[bin];
    const size_t binoff = offs[bin];
    const int wv = tid >> 6;
    const int ln = tid & 63;

    // load this thread's w_hh row (64 f32) into registers
    float wr[64];
    const float* wrow = whh + ((size_t)bin * 256 + tid) * 64;
    #pragma unroll
    for (int q = 0; q < 16; ++q) {
        float4 v = *reinterpret_cast<const float4*>(wrow + 4 * q);
        wr[4 * q + 0] = v.x; wr[4 * q + 1] = v.y;
        wr[4 * q + 2] = v.z; wr[4 * q + 3] = v.w;
    }
    const float4 wi = *reinterpret_cast<const float4*>(wih + ((size_t)bin * 256 + tid) * 4);
    const float bias = bih[bin * 256 + tid] + bhh[bin * 256 + tid];

    // init h = 0
    float* hf = &h4[0][0].x;
    hf[tid] = 0.0f;
    hf[tid + 256] = 0.0f;
    float c0 = 0.0f, c1 = 0.0f;

    for (int t = 0; t < T; ++t) {
        if ((t & 31) == 0) {
            // stage next 32 steps of x: thread -> (s = tid>>3, bb = tid&7)
            int s = tid >> 3, bb = tid & 7;
            xt4[tid] = *reinterpret_cast<const float4*>(
                xc + binoff + (((size_t)(t + s)) * BATCH + b0 + bb) * 4);
            __syncthreads();   // publish x tile (h already published by end-of-step barrier / init path)
        }
        if (t == 0) __syncthreads();  // publish h init on first iteration (t=0 hits tile barrier too; harmless extra)

        // ---- gates: each thread computes its row for 8 batch elements ----
        float acc[8];
        #pragma unroll
        for (int bb = 0; bb < 8; ++bb) {
            float a = bias;
            float4 xv = xt4[((t & 31) << 3) | bb];
            a = fmaf(wi.x, xv.x, a);
            a = fmaf(wi.y, xv.y, a);
            a = fmaf(wi.z, xv.z, a);
            a = fmaf(wi.w, xv.w, a);
            #pragma unroll
            for (int q = 0; q < 16; ++q) {
                float4 hv = h4[bb][q];
                a = fmaf(wr[4 * q + 0], hv.x, a);
                a = fmaf(wr[4 * q + 1], hv.y, a);
                a = fmaf(wr[4 * q + 2], hv.z, a);
                a = fmaf(wr[4 * q + 3], hv.w, a);
            }
            acc[bb] = a;
        }
        // activation: rows 0..63 i(sig), 64..127 f(sig), 128..191 g(tanh), 192..255 o(sig)
        if (wv == 2) {
            #pragma unroll
            for (int bb = 0; bb < 8; ++bb) gbuf[bb][tid] = tanh_f(acc[bb]);
        } else {
            #pragma unroll
            for (int bb = 0; bb < 8; ++bb) gbuf[bb][tid] = sigm_f(acc[bb]);
        }
        __syncthreads();

        // ---- update c,h: thread handles (b=wv, k=ln) and (b=wv+4, k=ln) ----
        {
            int b = wv;
            float gi = gbuf[b][ln], gf = gbuf[b][64 + ln];
            float gg = gbuf[b][128 + ln], go = gbuf[b][192 + ln];
            c0 = gf * c0 + gi * gg;
            hf[b * 64 + ln] = go * tanh_f(c0);
            b = wv + 4;
            gi = gbuf[b][ln]; gf = gbuf[b][64 + ln];
            gg = gbuf[b][128 + ln]; go = gbuf[b][192 + ln];
            c1 = gf * c1 + gi * gg;
            hf[b * 64 + ln] = go * tanh_f(c1);
        }
        __syncthreads();
    }

    // ---- linear head: out[b][bin] = h[b] . lin_w[bin] + lin_b[bin] ----
    if (tid < 8) {
        const float* hh = hf + tid * 64;
        const float* w = lw + bin * HID;
        float a = lb[bin];
        for (int k = 0; k < HID; ++k) a = fmaf(hh[k], w[k], a);
        out[(size_t)(b0 + tid) * NB + bin] = a;
    }
}

extern "C" void kernel_launch(void* const* d_in, const int* in_sizes, int n_in,
                              void* d_out, int out_size, void* d_ws, size_t ws_size,
                              hipStream_t stream) {
    const float* X   = (const float*)d_in[0];
    const float* cw  = (const float*)d_in[1];
    const float* cb  = (const float*)d_in[2];
    const float* wih = (const float*)d_in[3];
    const float* whh = (const float*)d_in[4];
    const float* bih = (const float*)d_in[5];
    const float* bhh = (const float*)d_in[6];
    const float* lw  = (const float*)d_in[7];
    const float* lb  = (const float*)d_in[8];
    float* out = (float*)d_out;
    float* xc  = (float*)d_ws;   // 7,864,320 floats = 31.5 MB

    pool_conv_kernel<<<BATCH, 256, 0, stream>>>(X, cw, cb, xc);
    lstm_kernel<<<NB * (BATCH / 8), 256, 0, stream>>>(xc, wih, whh, bih, bhh, lw, lb, out);
}

// Round 3
// 1170.327 us; speedup vs baseline: 2.2451x; 2.2451x over previous
//
#include <hip/hip_runtime.h>
#include <math.h>

#define BATCH 2048
#define CIN 14
#define LEN 2048
#define NB 4
#define HID 64
#define NEG 0.01f

// fast activations (f32, ~2ulp via v_exp_f32)
__device__ __forceinline__ float sigm_f(float x) { return 1.0f / (1.0f + __expf(-x)); }
__device__ __forceinline__ float tanh_f(float x) { return 1.0f - 2.0f / (1.0f + __expf(2.0f * x)); }

// ---------------- Kernel A: pool (hierarchical) + conv1d(k=3,pad=1) + LeakyReLU ----------------
// writes xc[bin] in layout [b][t][4] at float offsets base[bin] + b*T*4

__device__ __forceinline__ void conv_bin(const float* __restrict__ P, int ldp, int T,
                                         int bin,
                                         const float* __restrict__ cw,
                                         const float* __restrict__ cb,
                                         float* __restrict__ dst, int tid)
{
    const float* w = cw + (size_t)bin * 4 * CIN * 3;   // w[(f*CIN+ci)*3 + k]
    const float b0 = cb[bin * 4 + 0];
    const float b1 = cb[bin * 4 + 1];
    const float b2 = cb[bin * 4 + 2];
    const float b3 = cb[bin * 4 + 3];
    for (int t = tid; t < T; t += 256) {
        float a0 = b0, a1 = b1, a2 = b2, a3 = b3;
        for (int ci = 0; ci < CIN; ++ci) {
            float pm = (t > 0)     ? P[ci * ldp + t - 1] : 0.0f;
            float p0 =               P[ci * ldp + t];
            float pp = (t < T - 1) ? P[ci * ldp + t + 1] : 0.0f;
            const float* w0 = w + (0 * CIN + ci) * 3;
            const float* w1 = w + (1 * CIN + ci) * 3;
            const float* w2 = w + (2 * CIN + ci) * 3;
            const float* w3 = w + (3 * CIN + ci) * 3;
            a0 += w0[0] * pm + w0[1] * p0 + w0[2] * pp;
            a1 += w1[0] * pm + w1[1] * p0 + w1[2] * pp;
            a2 += w2[0] * pm + w2[1] * p0 + w2[2] * pp;
            a3 += w3[0] * pm + w3[1] * p0 + w3[2] * pp;
        }
        a0 = (a0 >= 0.0f) ? a0 : NEG * a0;
        a1 = (a1 >= 0.0f) ? a1 : NEG * a1;
        a2 = (a2 >= 0.0f) ? a2 : NEG * a2;
        a3 = (a3 >= 0.0f) ? a3 : NEG * a3;
        *reinterpret_cast<float4*>(dst + (size_t)t * 4) = make_float4(a0, a1, a2, a3);
    }
}

__global__ __launch_bounds__(256) void pool_conv_kernel(
    const float* __restrict__ X, const float* __restrict__ cw,
    const float* __restrict__ cb, float* __restrict__ xc)
{
    __shared__ float Pa[CIN][512];
    __shared__ float Pb[CIN][256];
    const int b = blockIdx.x;
    const int tid = threadIdx.x;

    // pool 2048 -> 512 (kernel == stride == 4), coalesced float4 reads
    for (int idx = tid; idx < CIN * 512; idx += 256) {
        int c = idx >> 9, t = idx & 511;
        const float4 v = *reinterpret_cast<const float4*>(X + ((size_t)b * CIN + c) * LEN + 4 * t);
        Pa[c][t] = 0.25f * (v.x + v.y + v.z + v.w);
    }
    __syncthreads();

    // bin 0 (T=512) from Pa; derive P256 -> Pb (both only READ Pa)
    conv_bin(&Pa[0][0], 512, 512, 0, cw, cb, xc + (size_t)b * 512 * 4, tid);
    for (int idx = tid; idx < CIN * 256; idx += 256) {
        int c = idx >> 8, t = idx & 255;
        Pb[c][t] = 0.5f * (Pa[c][2 * t] + Pa[c][2 * t + 1]);
    }
    __syncthreads();

    // bin 1 (T=256) from Pb; derive P128 into front of Pa
    conv_bin(&Pb[0][0], 256, 256, 1, cw, cb, xc + 4194304 + (size_t)b * 256 * 4, tid);
    for (int idx = tid; idx < CIN * 128; idx += 256) {
        int c = idx >> 7, t = idx & 127;
        Pa[c][t] = 0.5f * (Pb[c][2 * t] + Pb[c][2 * t + 1]);
    }
    __syncthreads();

    // bin 2 (T=128) from Pa-front; derive P64 into front of Pb
    conv_bin(&Pa[0][0], 512, 128, 2, cw, cb, xc + 6291456 + (size_t)b * 128 * 4, tid);
    for (int idx = tid; idx < CIN * 64; idx += 256) {
        int c = idx >> 6, t = idx & 63;
        Pb[c][t] = 0.5f * (Pa[c][2 * t] + Pa[c][2 * t + 1]);
    }
    __syncthreads();

    // bin 3 (T=64) from Pb-front
    conv_bin(&Pb[0][0], 256, 64, 3, cw, cb, xc + 7340032 + (size_t)b * 64 * 4, tid);
}

// ---------------- Kernel B: LSTM scan + linear head ----------------
// 2048 blocks, 256 threads = 4 waves. Block handles 4 batch elements of one bin.
// Wave w owns gate quadrant w (0=i,1=f,2=g,3=o): lane k holds W_hh row w*64+k
// (16 float4 = 64 VGPRs) and computes that gate row for all 4 batch elements.
// h[4][64] lives in LDS (broadcast reads). Wave w updates c/h of batch w only.
// Bin 0 occupies blockIdx 0..511 so the longest scan is dispatched first.

__global__ __launch_bounds__(256) void lstm_kernel(
    const float* __restrict__ xc,
    const float* __restrict__ wih, const float* __restrict__ whh,
    const float* __restrict__ bih, const float* __restrict__ bhh,
    const float* __restrict__ lw, const float* __restrict__ lb,
    float* __restrict__ out)
{
    __shared__ float4 h4[4][16];      // h[batch][64]
    __shared__ float  gl[4][4][64];   // [batch][gate][k]
    __shared__ float4 xs[4][64];      // x window: [batch][step]

    const int tid = threadIdx.x;
    const int w   = tid >> 6;   // wave = gate quadrant
    const int k   = tid & 63;
    const int bin = blockIdx.x >> 9;
    const int b0  = (blockIdx.x & 511) << 2;
    const int Ts[NB] = {512, 256, 128, 64};
    const size_t Bs[NB] = {0, 4194304, 6291456, 7340032};
    const int T = Ts[bin];
    const float* xbase = xc + Bs[bin];

    const int row = bin * 256 + w * 64 + k;
    float4 wr4[16];
    {
        const float* wrow = whh + (size_t)row * 64;
        #pragma unroll
        for (int q = 0; q < 16; ++q)
            wr4[q] = *reinterpret_cast<const float4*>(wrow + 4 * q);
    }
    const float4 wi = *reinterpret_cast<const float4*>(wih + (size_t)row * 4);
    const float bias = bih[row] + bhh[row];

    ((float*)h4)[tid] = 0.0f;   // 256 = 4*64
    float c = 0.0f;
    float h = 0.0f;

    for (int t = 0; t < T; ++t) {
        if ((t & 63) == 0) {
            const int bb = tid >> 6, s = tid & 63;
            xs[bb][s] = *reinterpret_cast<const float4*>(
                xbase + ((size_t)(b0 + bb) * T + t + s) * 4);
        }
        __syncthreads();   // A: h(t-1) + x window published

        const int tw = t & 63;
        float a0, a1, a2, a3;
        {
            float4 x0 = xs[0][tw];
            a0 = fmaf(wi.x, x0.x, bias); a0 = fmaf(wi.y, x0.y, a0);
            a0 = fmaf(wi.z, x0.z, a0);   a0 = fmaf(wi.w, x0.w, a0);
            float4 x1 = xs[1][tw];
            a1 = fmaf(wi.x, x1.x, bias); a1 = fmaf(wi.y, x1.y, a1);
            a1 = fmaf(wi.z, x1.z, a1);   a1 = fmaf(wi.w, x1.w, a1);
            float4 x2 = xs[2][tw];
            a2 = fmaf(wi.x, x2.x, bias); a2 = fmaf(wi.y, x2.y, a2);
            a2 = fmaf(wi.z, x2.z, a2);   a2 = fmaf(wi.w, x2.w, a2);
            float4 x3 = xs[3][tw];
            a3 = fmaf(wi.x, x3.x, bias); a3 = fmaf(wi.y, x3.y, a3);
            a3 = fmaf(wi.z, x3.z, a3);   a3 = fmaf(wi.w, x3.w, a3);
        }
        #pragma unroll
        for (int q = 0; q < 16; ++q) {
            const float4 wq = wr4[q];
            float4 hv;
            hv = h4[0][q];
            a0 = fmaf(wq.x, hv.x, a0); a0 = fmaf(wq.y, hv.y, a0);
            a0 = fmaf(wq.z, hv.z, a0); a0 = fmaf(wq.w, hv.w, a0);
            hv = h4[1][q];
            a1 = fmaf(wq.x, hv.x, a1); a1 = fmaf(wq.y, hv.y, a1);
            a1 = fmaf(wq.z, hv.z, a1); a1 = fmaf(wq.w, hv.w, a1);
            hv = h4[2][q];
            a2 = fmaf(wq.x, hv.x, a2); a2 = fmaf(wq.y, hv.y, a2);
            a2 = fmaf(wq.z, hv.z, a2); a2 = fmaf(wq.w, hv.w, a2);
            hv = h4[3][q];
            a3 = fmaf(wq.x, hv.x, a3); a3 = fmaf(wq.y, hv.y, a3);
            a3 = fmaf(wq.z, hv.z, a3); a3 = fmaf(wq.w, hv.w, a3);
        }

        float g0, g1, g2, g3;
        if (w == 2) { g0 = tanh_f(a0); g1 = tanh_f(a1); g2 = tanh_f(a2); g3 = tanh_f(a3); }
        else        { g0 = sigm_f(a0); g1 = sigm_f(a1); g2 = sigm_f(a2); g3 = sigm_f(a3); }
        gl[0][w][k] = g0; gl[1][w][k] = g1; gl[2][w][k] = g2; gl[3][w][k] = g3;
        __syncthreads();   // B: gates published

        // wave w updates batch w's state
        const float gi = gl[w][0][k], gf = gl[w][1][k];
        const float gg = gl[w][2][k], go = gl[w][3][k];
        c = fmaf(gf, c, gi * gg);
        h = go * tanh_f(c);
        ((float*)h4)[w * 64 + k] = h;
        // published by barrier A of next iteration
    }

    // linear head: wave w -> batch b0+w  (NOTE: + lin_b — the round-2 bug)
    float v = h * lw[bin * HID + k];
    #pragma unroll
    for (int off = 32; off > 0; off >>= 1) v += __shfl_down(v, off);
    if (k == 0) out[(size_t)(b0 + w) * NB + bin] = v + lb[bin];
}

extern "C" void kernel_launch(void* const* d_in, const int* in_sizes, int n_in,
                              void* d_out, int out_size, void* d_ws, size_t ws_size,
                              hipStream_t stream) {
    const float* X   = (const float*)d_in[0];
    const float* cw  = (const float*)d_in[1];
    const float* cb  = (const float*)d_in[2];
    const float* wih = (const float*)d_in[3];
    const float* whh = (const float*)d_in[4];
    const float* bih = (const float*)d_in[5];
    const float* bhh = (const float*)d_in[6];
    const float* lw  = (const float*)d_in[7];
    const float* lb  = (const float*)d_in[8];
    float* out = (float*)d_out;
    float* xc  = (float*)d_ws;   // 7,864,320 floats = 31.5 MB

    pool_conv_kernel<<<BATCH, 256, 0, stream>>>(X, cw, cb, xc);
    lstm_kernel<<<NB * (BATCH / 4), 256, 0, stream>>>(xc, wih, whh, bih, bhh, lw, lb, out);
}